// Round 1
// baseline (382.702 us; speedup 1.0000x reference)
//
#include <hip/hip_runtime.h>
#include <math.h>

#define N_CH 17
#define IN_H 64
#define IN_W 32
#define OUT_H 16
#define OUT_W 8
#define HW (OUT_H * OUT_W)   // 128
#define S_IN_STRIDE 33       // pad 32->33: conflict-free column reads
#define S_TMP_STRIDE 33

// 4x antialiased linear downsample (jax.image.resize 'linear', antialias=True):
// triangle kernel scaled by 4 -> 8 taps interior, renormalized 6 taps at edges.
// Uniform 8-tap form: start s = clamp(4o-2, 0, in-8), zero-padded edge weights.
__device__ __forceinline__ void get_weights(int o, int out_n, int in_n,
                                            float* w, int* s) {
    if (o == 0) {
        *s = 0;
        w[0] = 5.f/28.f; w[1] = 7.f/28.f; w[2] = 7.f/28.f; w[3] = 5.f/28.f;
        w[4] = 3.f/28.f; w[5] = 1.f/28.f; w[6] = 0.f;      w[7] = 0.f;
    } else if (o == out_n - 1) {
        *s = in_n - 8;
        w[0] = 0.f;      w[1] = 0.f;      w[2] = 1.f/28.f; w[3] = 3.f/28.f;
        w[4] = 5.f/28.f; w[5] = 7.f/28.f; w[6] = 7.f/28.f; w[7] = 5.f/28.f;
    } else {
        *s = 4 * o - 2;
        w[0] = 1.f/32.f; w[1] = 3.f/32.f; w[2] = 5.f/32.f; w[3] = 7.f/32.f;
        w[4] = 7.f/32.f; w[5] = 5.f/32.f; w[6] = 3.f/32.f; w[7] = 1.f/32.f;
    }
}

__global__ __launch_bounds__(256)
void heatmap_kernel(const float* __restrict__ x,
                    float* __restrict__ out_heat,   // [N,3,16,8]
                    float* __restrict__ out_mr,     // [N,3]
                    float* __restrict__ out_mi) {   // [N,17,2]
    const int n = blockIdx.x;
    const int t = threadIdx.x;

    __shared__ float s_in[IN_H * S_IN_STRIDE];    // 8448 B
    __shared__ float s_tmp[OUT_H * S_TMP_STRIDE]; // 2112 B
    __shared__ float s_red[HW];
    __shared__ float s_chmax[N_CH];
    __shared__ float s_bcast;

    // Stage 1 (reduce H 64->16): thread t computes tmp rows (t>>5) and 8+(t>>5),
    // column t&31. Weights are channel-invariant -> precompute.
    float wA[8], wB[8], wC[8];
    int sA, sB, sC = 0;
    get_weights(t >> 5, OUT_H, IN_H, wA, &sA);
    get_weights(8 + (t >> 5), OUT_H, IN_H, wB, &sB);
    // Stage 2 (reduce W 32->8): thread t<128 owns (orow=t>>3, ocol=t&7)
    if (t < HW) get_weights(t & 7, OUT_W, IN_W, wC, &sC);

    const float* xn = x + (size_t)n * N_CH * IN_H * IN_W;

    float gs0 = 0.f, gs1 = 0.f, gs2 = 0.f;  // group spatial sums (reg-resident)

    // preload channel 0 (2048 floats = 512 float4; 2 per thread)
    float4 la = ((const float4*)xn)[t];
    float4 lb = ((const float4*)xn)[t + 256];

    for (int c = 0; c < N_CH; ++c) {
        // registers -> LDS (padded row stride)
        {
            int i0 = 4 * t;
            float* p = &s_in[(i0 >> 5) * S_IN_STRIDE + (i0 & 31)];
            p[0] = la.x; p[1] = la.y; p[2] = la.z; p[3] = la.w;
            int i1 = 4 * (t + 256);
            p = &s_in[(i1 >> 5) * S_IN_STRIDE + (i1 & 31)];
            p[0] = lb.x; p[1] = lb.y; p[2] = lb.z; p[3] = lb.w;
        }
        __syncthreads();

        // prefetch next channel (overlaps both filter stages + reductions)
        if (c + 1 < N_CH) {
            const float4* src = (const float4*)(xn + (size_t)(c + 1) * IN_H * IN_W);
            la = src[t];
            lb = src[t + 256];
        }

        // stage 1: filter along H
        {
            int col = t & 31;
            float acc = 0.f, acc2 = 0.f;
#pragma unroll
            for (int d = 0; d < 8; ++d)
                acc += wA[d] * s_in[(sA + d) * S_IN_STRIDE + col];
#pragma unroll
            for (int d = 0; d < 8; ++d)
                acc2 += wB[d] * s_in[(sB + d) * S_IN_STRIDE + col];
            s_tmp[(t >> 5) * S_TMP_STRIDE + col] = acc;
            s_tmp[(8 + (t >> 5)) * S_TMP_STRIDE + col] = acc2;
        }
        __syncthreads();

        // stage 2: filter along W; accumulate group sums; stage for argmax
        if (t < HW) {
            int orow = t >> 3;
            float acc = 0.f;
#pragma unroll
            for (int d = 0; d < 8; ++d)
                acc += wC[d] * s_tmp[orow * S_TMP_STRIDE + sC + d];
            s_red[t] = acc;
            if (c < 5)       gs0 += acc;
            else if (c < 11) gs1 += acc;
            else             gs2 += acc;
        }
        __syncthreads();

        // per-channel max + argmax (first-max tiebreak), wave 0 only
        if (t < 64) {
            float v0 = s_red[t], v1 = s_red[t + 64];
            float bv; int bi;
            if (v1 > v0) { bv = v1; bi = t + 64; } else { bv = v0; bi = t; }
#pragma unroll
            for (int off = 32; off >= 1; off >>= 1) {
                float ov = __shfl_down(bv, off);
                int   oi = __shfl_down(bi, off);
                if (ov > bv || (ov == bv && oi < bi)) { bv = ov; bi = oi; }
            }
            if (t == 0) {
                s_chmax[c] = bv;
                float* mi = out_mi + ((size_t)n * N_CH + c) * 2;
                mi[0] = (float)(bi & 7);   // x = idx % 8
                mi[1] = (float)(bi >> 3);  // y = idx / 8
            }
        }
        __syncthreads();
    }

    // group means of per-channel maxes
    if (t < 3) {
        int lo = (t == 0) ? 0 : ((t == 1) ? 5 : 11);
        int hi = (t == 0) ? 5 : ((t == 1) ? 11 : 17);
        float acc = 0.f;
        for (int c = lo; c < hi; ++c) acc += s_chmax[c];
        out_mr[(size_t)n * 3 + t] = acc / (float)(hi - lo);
    }

    // softmax over the 128 spatial positions, per group
    float gsv[3] = {gs0, gs1, gs2};
#pragma unroll 1
    for (int g = 0; g < 3; ++g) {
        if (t < HW) s_red[t] = gsv[g];
        __syncthreads();
        if (t < 64) {
            float bv = fmaxf(s_red[t], s_red[t + 64]);
#pragma unroll
            for (int off = 32; off >= 1; off >>= 1)
                bv = fmaxf(bv, __shfl_down(bv, off));
            if (t == 0) s_bcast = bv;
        }
        __syncthreads();
        float m = s_bcast;
        float e = 0.f;
        if (t < HW) { e = expf(gsv[g] - m); s_red[t] = e; }
        __syncthreads();
        if (t < 64) {
            float sv = s_red[t] + s_red[t + 64];
#pragma unroll
            for (int off = 32; off >= 1; off >>= 1)
                sv += __shfl_down(sv, off);
            if (t == 0) s_bcast = sv;
        }
        __syncthreads();
        if (t < HW)
            out_heat[((size_t)n * 3 + g) * HW + t] = e / s_bcast;
        __syncthreads();
    }
}

extern "C" void kernel_launch(void* const* d_in, const int* in_sizes, int n_in,
                              void* d_out, int out_size, void* d_ws, size_t ws_size,
                              hipStream_t stream) {
    const float* x = (const float*)d_in[0];
    float* out = (float*)d_out;
    const int N = in_sizes[0] / (N_CH * IN_H * IN_W);  // 2048
    float* out_heat = out;                               // N*3*128
    float* out_mr   = out_heat + (size_t)N * 3 * HW;     // N*3
    float* out_mi   = out_mr + (size_t)N * 3;            // N*17*2
    heatmap_kernel<<<dim3(N), dim3(256), 0, stream>>>(x, out_heat, out_mr, out_mi);
}